// Round 1
// baseline (2874.726 us; speedup 1.0000x reference)
//
#include <hip/hip_runtime.h>
#include <hip/hip_bf16.h>

// MoE: E=64 experts, top-2, T=B*S=8192 tokens, D=1024, DFF=1408, CAP=1024.
// Round 1: fully-f32 correctness-first implementation.
//   gate -> me-reduce -> finalize(prefix+l_aux) -> scatter -> ffn1 -> ffn2.
// Compacted row layout (only actual routed pairs, 16384 rows total).

#define S_ 2048
#define B_ 4
#define D_ 1024
#define DFF_ 1408
#define E_ 64
#define T_ 8192
#define KTOP_ 2
#define CAP_ 1024
#define NPAIR_ (T_*KTOP_)

// ---------------- workspace layout (bytes) ----------------
constexpr size_t OFF_PROBS  = 0;                                   // T*E f32 = 2 MB
constexpr size_t OFF_PE     = OFF_PROBS + (size_t)T_*E_*4;         // NPAIR int
constexpr size_t OFF_PW     = OFF_PE + (size_t)NPAIR_*4;           // NPAIR f32
constexpr size_t OFF_COUNTS = OFF_PW + (size_t)NPAIR_*4;           // 64 int
constexpr size_t OFF_CURSOR = OFF_COUNTS + 256;                    // 64 int
constexpr size_t OFF_OFFS   = OFF_CURSOR + 256;                    // 64 int
constexpr size_t OFF_MESUM  = OFF_OFFS + 256;                      // 64 f32
constexpr size_t OFF_ROWTOK = OFF_MESUM + 256;                     // NPAIR int
constexpr size_t OFF_ROWW   = OFF_ROWTOK + (size_t)NPAIR_*4;       // NPAIR f32
constexpr size_t OFF_XBUF   = OFF_ROWW + (size_t)NPAIR_*4;         // NPAIR*D f32 = 64 MB
constexpr size_t OFF_H      = OFF_XBUF + (size_t)NPAIR_*D_*4;      // NPAIR*DFF f32 = 92 MB

// ---------------- gate: logits -> softmax -> top2 ----------------
__global__ __launch_bounds__(64) void gate_kernel(
    const float* __restrict__ x, const float* __restrict__ Wg,
    float* __restrict__ probs, int* __restrict__ pe, float* __restrict__ pw,
    int* __restrict__ counts) {
  int t = blockIdx.x;
  int lane = threadIdx.x;
  int b = t >> 11, s = t & (S_ - 1);
  const float* tok = x + (size_t)(s * B_ + b) * D_;
  __shared__ float tk[D_];
  for (int i = lane; i < D_; i += 64) tk[i] = tok[i];
  __syncthreads();
  float acc = 0.f;
  #pragma unroll 8
  for (int d = 0; d < D_; ++d) acc += tk[d] * Wg[d * E_ + lane];
  // softmax over 64 lanes
  float m = acc;
  for (int o = 32; o; o >>= 1) m = fmaxf(m, __shfl_xor(m, o));
  float p = expf(acc - m);
  float ssum = p;
  for (int o = 32; o; o >>= 1) ssum += __shfl_xor(ssum, o);
  p /= ssum;
  probs[(size_t)t * E_ + lane] = p;
  // top-1 (tie -> lower index)
  float v1 = p; int i1 = lane;
  for (int o = 32; o; o >>= 1) {
    float ov = __shfl_xor(v1, o); int oi = __shfl_xor(i1, o);
    if (ov > v1 || (ov == v1 && oi < i1)) { v1 = ov; i1 = oi; }
  }
  // top-2
  float v2 = (lane == i1) ? -1.f : p; int i2 = lane;
  for (int o = 32; o; o >>= 1) {
    float ov = __shfl_xor(v2, o); int oi = __shfl_xor(i2, o);
    if (ov > v2 || (ov == v2 && oi < i2)) { v2 = ov; i2 = oi; }
  }
  if (lane == 0) {
    float wsum = v1 + v2;
    pe[2 * t]     = i1; pw[2 * t]     = v1 / wsum;
    pe[2 * t + 1] = i2; pw[2 * t + 1] = v2 / wsum;
    atomicAdd(&counts[i1], 1);
    atomicAdd(&counts[i2], 1);
  }
}

// ---------------- deterministic column reduce for me ----------------
__global__ __launch_bounds__(256) void me_kernel(const float* __restrict__ probs,
                                                 float* __restrict__ mesum) {
  int e = blockIdx.x, tid = threadIdx.x;
  float a = 0.f;
  for (int t = tid; t < T_; t += 256) a += probs[(size_t)t * E_ + e];
  __shared__ float red[256];
  red[tid] = a; __syncthreads();
  for (int s = 128; s; s >>= 1) {
    if (tid < s) red[tid] += red[tid + s];
    __syncthreads();
  }
  if (tid == 0) mesum[e] = red[0];
}

// ---------------- finalize: prefix offsets + l_aux ----------------
__global__ __launch_bounds__(64) void finalize_kernel(
    const int* __restrict__ counts, const float* __restrict__ mesum,
    int* __restrict__ offs, float* __restrict__ laux_out) {
  int lane = threadIdx.x;
  int c = counts[lane];
  int ck = min(c, CAP_);            // kept rows per expert
  int pfx = ck;
  for (int o = 1; o < 64; o <<= 1) {
    int v = __shfl_up(pfx, o);
    if (lane >= o) pfx += v;
  }
  offs[lane] = pfx - ck;            // exclusive prefix of kept counts
  float contrib = (mesum[lane] / (float)T_) * ((float)c / (float)(T_ * KTOP_));
  for (int o = 32; o; o >>= 1) contrib += __shfl_xor(contrib, o);
  if (lane == 0) laux_out[0] = (float)E_ * contrib;
}

// ---------------- scatter: compact gather into xbuf ----------------
__global__ __launch_bounds__(64) void scatter_kernel(
    const float* __restrict__ x, const int* __restrict__ pe, const float* __restrict__ pw,
    const int* __restrict__ offs, int* __restrict__ cursor,
    int* __restrict__ rowtok, float* __restrict__ roww, float* __restrict__ xbuf) {
  int p = blockIdx.x;
  int lane = threadIdx.x;
  __shared__ int srow;
  int e = pe[p];
  if (lane == 0) {
    int slot = atomicAdd(&cursor[e], 1);
    int row = (slot < CAP_) ? (offs[e] + slot) : -1;
    if (row >= 0) { rowtok[row] = p >> 1; roww[row] = pw[p]; }
    srow = row;
  }
  __syncthreads();
  int row = srow;
  if (row < 0) return;
  int t = p >> 1;
  int b = t >> 11, s = t & (S_ - 1);
  const float* src = x + (size_t)(s * B_ + b) * D_;
  float* dst = xbuf + (size_t)row * D_;
  for (int i = lane; i < D_; i += 64) dst[i] = src[i];
}

// ---------------- ffn1: h = silu(xb@W1) * (xb@W3) ----------------
__global__ __launch_bounds__(256) void ffn1_kernel(
    const float* __restrict__ xbuf, const float* __restrict__ W1, const float* __restrict__ W3,
    const int* __restrict__ counts, const int* __restrict__ offs, float* __restrict__ h) {
  int e = blockIdx.z;
  int Me = min(counts[e], CAP_);
  int m0 = blockIdx.y * 64;
  if (m0 >= Me) return;
  int n0 = blockIdx.x * 64;
  int base = offs[e];
  const float* A  = xbuf + (size_t)base * D_;
  const float* B1 = W1 + (size_t)e * D_ * DFF_;
  const float* B3 = W3 + (size_t)e * D_ * DFF_;
  __shared__ float As[16][68];
  __shared__ float B1s[16][68];
  __shared__ float B3s[16][68];
  int tid = threadIdx.x;
  int tx = tid & 15, ty = tid >> 4;     // tx->n group, ty->m group
  float acc1[4][4] = {{0.f}}, acc3[4][4] = {{0.f}};
  for (int k0 = 0; k0 < D_; k0 += 16) {
    for (int i = tid; i < 64 * 16; i += 256) {
      int m = i >> 4, kk = i & 15;
      int row = m0 + m;
      As[kk][m] = (row < Me) ? A[(size_t)row * D_ + k0 + kk] : 0.f;
    }
    for (int i = tid; i < 16 * 64; i += 256) {
      int kk = i >> 6, n = i & 63;
      B1s[kk][n] = B1[(size_t)(k0 + kk) * DFF_ + n0 + n];
      B3s[kk][n] = B3[(size_t)(k0 + kk) * DFF_ + n0 + n];
    }
    __syncthreads();
    #pragma unroll
    for (int kk = 0; kk < 16; ++kk) {
      float a[4], b1[4], b3[4];
      #pragma unroll
      for (int i = 0; i < 4; ++i) a[i] = As[kk][ty * 4 + i];
      #pragma unroll
      for (int j = 0; j < 4; ++j) { b1[j] = B1s[kk][tx * 4 + j]; b3[j] = B3s[kk][tx * 4 + j]; }
      #pragma unroll
      for (int i = 0; i < 4; ++i)
        #pragma unroll
        for (int j = 0; j < 4; ++j) {
          acc1[i][j] += a[i] * b1[j];
          acc3[i][j] += a[i] * b3[j];
        }
    }
    __syncthreads();
  }
  for (int i = 0; i < 4; ++i) {
    int m = m0 + ty * 4 + i;
    if (m >= Me) continue;
    for (int j = 0; j < 4; ++j) {
      int f = n0 + tx * 4 + j;
      float a = acc1[i][j];
      float sg = a / (1.f + expf(-a));   // silu
      h[(size_t)(base + m) * DFF_ + f] = sg * acc3[i][j];
    }
  }
}

// ---------------- ffn2: y += w * (h@W2) ----------------
__global__ __launch_bounds__(256) void ffn2_kernel(
    const float* __restrict__ h, const float* __restrict__ W2,
    const int* __restrict__ counts, const int* __restrict__ offs,
    const int* __restrict__ rowtok, const float* __restrict__ roww,
    float* __restrict__ y) {
  int e = blockIdx.z;
  int Me = min(counts[e], CAP_);
  int m0 = blockIdx.y * 64;
  if (m0 >= Me) return;
  int n0 = blockIdx.x * 64;
  int base = offs[e];
  const float* A  = h + (size_t)base * DFF_;
  const float* Bw = W2 + (size_t)e * DFF_ * D_;
  __shared__ float As[16][68];
  __shared__ float Bs[16][68];
  int tid = threadIdx.x;
  int tx = tid & 15, ty = tid >> 4;
  float acc[4][4] = {{0.f}};
  for (int k0 = 0; k0 < DFF_; k0 += 16) {
    for (int i = tid; i < 64 * 16; i += 256) {
      int m = i >> 4, kk = i & 15;
      int row = m0 + m;
      As[kk][m] = (row < Me) ? A[(size_t)row * DFF_ + k0 + kk] : 0.f;
    }
    for (int i = tid; i < 16 * 64; i += 256) {
      int kk = i >> 6, n = i & 63;
      Bs[kk][n] = Bw[(size_t)(k0 + kk) * D_ + n0 + n];
    }
    __syncthreads();
    #pragma unroll
    for (int kk = 0; kk < 16; ++kk) {
      float a[4], b[4];
      #pragma unroll
      for (int i = 0; i < 4; ++i) a[i] = As[kk][ty * 4 + i];
      #pragma unroll
      for (int j = 0; j < 4; ++j) b[j] = Bs[kk][tx * 4 + j];
      #pragma unroll
      for (int i = 0; i < 4; ++i)
        #pragma unroll
        for (int j = 0; j < 4; ++j) acc[i][j] += a[i] * b[j];
    }
    __syncthreads();
  }
  for (int i = 0; i < 4; ++i) {
    int m = m0 + ty * 4 + i;
    if (m >= Me) continue;
    int row = base + m;
    int t = rowtok[row];
    float w = roww[row];
    int b = t >> 11, s = t & (S_ - 1);
    float* yrow = y + (size_t)(s * B_ + b) * D_;
    for (int j = 0; j < 4; ++j) {
      int d = n0 + tx * 4 + j;
      atomicAdd(&yrow[d], w * acc[i][j]);   // exactly 2 adds/element -> deterministic
    }
  }
}

extern "C" void kernel_launch(void* const* d_in, const int* in_sizes, int n_in,
                              void* d_out, int out_size, void* d_ws, size_t ws_size,
                              hipStream_t stream) {
  const float* x  = (const float*)d_in[0];
  const float* Wg = (const float*)d_in[1];
  const float* W1 = (const float*)d_in[2];
  const float* W3 = (const float*)d_in[3];
  const float* W2 = (const float*)d_in[4];
  float* y = (float*)d_out;
  float* laux = y + (size_t)S_ * B_ * D_;

  char* ws = (char*)d_ws;
  float* probs  = (float*)(ws + OFF_PROBS);
  int*   pe     = (int*)  (ws + OFF_PE);
  float* pw     = (float*)(ws + OFF_PW);
  int*   counts = (int*)  (ws + OFF_COUNTS);
  int*   cursor = (int*)  (ws + OFF_CURSOR);
  int*   offs   = (int*)  (ws + OFF_OFFS);
  float* mesum  = (float*)(ws + OFF_MESUM);
  int*   rowtok = (int*)  (ws + OFF_ROWTOK);
  float* roww   = (float*)(ws + OFF_ROWW);
  float* xbuf   = (float*)(ws + OFF_XBUF);
  float* h      = (float*)(ws + OFF_H);

  // zero y (+laux slot) and the atomic counters (counts,cursor contiguous 512B)
  hipMemsetAsync(d_out, 0, (size_t)out_size * sizeof(float), stream);
  hipMemsetAsync(counts, 0, 512, stream);

  gate_kernel<<<T_, 64, 0, stream>>>(x, Wg, probs, pe, pw, counts);
  me_kernel<<<E_, 256, 0, stream>>>(probs, mesum);
  finalize_kernel<<<1, 64, 0, stream>>>(counts, mesum, offs, laux);
  scatter_kernel<<<NPAIR_, 64, 0, stream>>>(x, pe, pw, offs, cursor, rowtok, roww, xbuf);
  ffn1_kernel<<<dim3(DFF_ / 64, CAP_ / 64, E_), 256, 0, stream>>>(xbuf, W1, W3, counts, offs, h);
  ffn2_kernel<<<dim3(D_ / 64, CAP_ / 64, E_), 256, 0, stream>>>(h, W2, counts, offs, rowtok, roww, y);
}

// Round 2
// 910.753 us; speedup vs baseline: 3.1564x; 3.1564x over previous
//
#include <hip/hip_runtime.h>
#include <hip/hip_bf16.h>

// MoE E=64, top-2, T=8192, D=1024, DFF=1408. Round 2: bf16 MFMA FFN.
// gate(f32) -> me -> finalize(l_aux) -> scatter(x->bf16, expert-padded rows)
// -> ffn1 (x@W1, x@W3 fused + SiLU -> h bf16) -> ffn2 (h@W2 -> atomic y).
// Weights are f32 in HBM; converted to bf16 in registers during LDS staging.
// LDS uses fragment-contiguous 16x32 subtiles (1KB): lane l <-> byte l*16,
// conflict-free for both ds_write_b128 staging and ds_read_b128 frag reads.

#define S_ 2048
#define B_ 4
#define D_ 1024
#define DFF_ 1408
#define E_ 64
#define T_ 8192
#define KTOP_ 2
#define NPAIR_ (T_*KTOP_)
#define PAD_ 384              // rows/expert (mean 256, sigma 16 -> +8 sigma)
#define ROWS_ (E_*PAD_)       // 24576

#define BM 128
#define BN 128
#define BK 32

typedef __attribute__((ext_vector_type(8))) short short8;
typedef __attribute__((ext_vector_type(4))) float f32x4;
typedef __attribute__((ext_vector_type(4))) unsigned short us4;

// ---------------- workspace layout (bytes) ----------------
constexpr size_t OFF_PROBS  = 0;                                   // T*E f32 = 2MB
constexpr size_t OFF_PE     = OFF_PROBS + (size_t)T_*E_*4;         // NPAIR int
constexpr size_t OFF_PW     = OFF_PE + (size_t)NPAIR_*4;           // NPAIR f32
constexpr size_t OFF_COUNTS = OFF_PW + (size_t)NPAIR_*4;           // 64 int
constexpr size_t OFF_CURSOR = OFF_COUNTS + 256;                    // 64 int
constexpr size_t OFF_MESUM  = OFF_CURSOR + 256;                    // 64 f32
constexpr size_t OFF_ROWTOK = OFF_MESUM + 256;                     // ROWS_ int
constexpr size_t OFF_ROWW   = OFF_ROWTOK + (size_t)ROWS_*4;        // ROWS_ f32
constexpr size_t OFF_XBUF   = OFF_ROWW + (size_t)ROWS_*4;          // ROWS_*D bf16 = 50MB
constexpr size_t OFF_H      = OFF_XBUF + (size_t)ROWS_*D_*2;       // ROWS_*DFF bf16 = 69MB
// total ~122 MB (< round-1's 160 MB which fit)

__device__ __forceinline__ unsigned short f2bf(float f) {
  unsigned u = __float_as_uint(f);
  unsigned r = (u + 0x7FFFu + ((u >> 16) & 1u)) >> 16;   // RNE
  return (unsigned short)r;
}

// ---------------- gate: logits -> softmax -> top2 ----------------
__global__ __launch_bounds__(64) void gate_kernel(
    const float* __restrict__ x, const float* __restrict__ Wg,
    float* __restrict__ probs, int* __restrict__ pe, float* __restrict__ pw,
    int* __restrict__ counts) {
  int t = blockIdx.x;
  int lane = threadIdx.x;
  int b = t >> 11, s = t & (S_ - 1);
  const float* tok = x + (size_t)(s * B_ + b) * D_;
  __shared__ float tk[D_];
  for (int i = lane; i < D_; i += 64) tk[i] = tok[i];
  __syncthreads();
  float acc = 0.f;
  #pragma unroll 8
  for (int d = 0; d < D_; ++d) acc += tk[d] * Wg[d * E_ + lane];
  float m = acc;
  for (int o = 32; o; o >>= 1) m = fmaxf(m, __shfl_xor(m, o));
  float p = expf(acc - m);
  float ssum = p;
  for (int o = 32; o; o >>= 1) ssum += __shfl_xor(ssum, o);
  p /= ssum;
  probs[(size_t)t * E_ + lane] = p;
  float v1 = p; int i1 = lane;
  for (int o = 32; o; o >>= 1) {
    float ov = __shfl_xor(v1, o); int oi = __shfl_xor(i1, o);
    if (ov > v1 || (ov == v1 && oi < i1)) { v1 = ov; i1 = oi; }
  }
  float v2 = (lane == i1) ? -1.f : p; int i2 = lane;
  for (int o = 32; o; o >>= 1) {
    float ov = __shfl_xor(v2, o); int oi = __shfl_xor(i2, o);
    if (ov > v2 || (ov == v2 && oi < i2)) { v2 = ov; i2 = oi; }
  }
  if (lane == 0) {
    float wsum = v1 + v2;
    pe[2 * t]     = i1; pw[2 * t]     = v1 / wsum;
    pe[2 * t + 1] = i2; pw[2 * t + 1] = v2 / wsum;
    atomicAdd(&counts[i1], 1);
    atomicAdd(&counts[i2], 1);
  }
}

// ---------------- deterministic column reduce for me ----------------
__global__ __launch_bounds__(256) void me_kernel(const float* __restrict__ probs,
                                                 float* __restrict__ mesum) {
  int e = blockIdx.x, tid = threadIdx.x;
  float a = 0.f;
  for (int t = tid; t < T_; t += 256) a += probs[(size_t)t * E_ + e];
  __shared__ float red[256];
  red[tid] = a; __syncthreads();
  for (int s = 128; s; s >>= 1) {
    if (tid < s) red[tid] += red[tid + s];
    __syncthreads();
  }
  if (tid == 0) mesum[e] = red[0];
}

// ---------------- finalize: l_aux ----------------
__global__ __launch_bounds__(64) void finalize_kernel(
    const int* __restrict__ counts, const float* __restrict__ mesum,
    float* __restrict__ laux_out) {
  int lane = threadIdx.x;
  float contrib = (mesum[lane] / (float)T_) * ((float)counts[lane] / (float)(T_ * KTOP_));
  for (int o = 32; o; o >>= 1) contrib += __shfl_xor(contrib, o);
  if (lane == 0) laux_out[0] = (float)E_ * contrib;
}

// ---------------- scatter: gather token rows -> bf16 padded xbuf ----------------
__global__ __launch_bounds__(64) void scatter_kernel(
    const float* __restrict__ x, const int* __restrict__ pe, const float* __restrict__ pw,
    int* __restrict__ cursor, int* __restrict__ rowtok, float* __restrict__ roww,
    unsigned short* __restrict__ xbuf) {
  int p = blockIdx.x;
  int lane = threadIdx.x;
  __shared__ int srow;
  if (lane == 0) {
    int e = pe[p];
    int slot = atomicAdd(&cursor[e], 1);
    int row = (slot < PAD_) ? (e * PAD_ + slot) : -1;
    if (row >= 0) { rowtok[row] = p >> 1; roww[row] = pw[p]; }
    srow = row;
  }
  __syncthreads();
  int row = srow;
  if (row < 0) return;
  int t = p >> 1;
  int b = t >> 11, s = t & (S_ - 1);
  const float4* src = (const float4*)(x + (size_t)(s * B_ + b) * D_);
  unsigned short* dst = xbuf + (size_t)row * D_;
  for (int i = lane; i < D_ / 4; i += 64) {
    float4 v = src[i];
    us4 o;
    o.x = f2bf(v.x); o.y = f2bf(v.y); o.z = f2bf(v.z); o.w = f2bf(v.w);
    *(us4*)(dst + i * 4) = o;
  }
}

// ---------------- ffn1: h = silu(x@W1) * (x@W3), bf16 MFMA ----------------
__global__ __launch_bounds__(256) void ffn1_kernel(
    const unsigned short* __restrict__ xbuf, const float* __restrict__ W1,
    const float* __restrict__ W3, const int* __restrict__ counts,
    unsigned short* __restrict__ h) {
  int e = blockIdx.z;
  int Me = min(counts[e], PAD_);
  int m0 = blockIdx.y * BM;
  if (m0 >= Me) return;
  int n0 = blockIdx.x * BN;

  const unsigned short* A = xbuf + (size_t)(e * PAD_ + m0) * D_;
  const float* B1 = W1 + (size_t)e * D_ * DFF_ + n0;
  const float* B3 = W3 + (size_t)e * D_ * DFF_ + n0;
  unsigned short* hptr = h + (size_t)e * PAD_ * DFF_;

  __shared__ short Als[BM * BK];   // 8KB fragment-contiguous
  __shared__ short B1s[BK * BN];   // 8KB
  __shared__ short B3s[BK * BN];   // 8KB

  int tid = threadIdx.x;
  int lane = tid & 63;
  int wv = tid >> 6, wr = wv >> 1, wc = wv & 1;

  // A staging: unit (row, kseg): row = tid>>2 (+64), kseg = tid&3
  int arow = tid >> 2, akseg = tid & 3;
  int aoff0 = ((arow >> 4) << 10) + ((akseg << 4) + (arow & 15)) * 16;
  int aoff1 = aoff0 + (4 << 10);   // row+64: subtile +4, same in-subtile pos
  // B staging: col c = tid&127, ksegs tid>>7 and tid>>7 + 2
  int bc = tid & 127, bs0 = tid >> 7;
  int boff0 = ((bc >> 4) << 10) + ((bs0 << 4) + (bc & 15)) * 16;
  int boff1 = boff0 + (2 << 4) * 16;   // kseg+2 -> +512B

  f32x4 acc1[4][4] = {};
  f32x4 acc3[4][4] = {};

  for (int k0 = 0; k0 < D_; k0 += BK) {
    __syncthreads();
    // A: two bf16x8 direct loads
    short8 av0 = *(const short8*)(A + (size_t)arow * D_ + k0 + akseg * 8);
    short8 av1 = *(const short8*)(A + (size_t)(arow + 64) * D_ + k0 + akseg * 8);
    // B: 8 strided f32 per unit, convert to bf16, pack
    const float* p10 = B1 + (size_t)(k0 + bs0 * 8) * DFF_ + bc;
    const float* p11 = B1 + (size_t)(k0 + (bs0 + 2) * 8) * DFF_ + bc;
    const float* p30 = B3 + (size_t)(k0 + bs0 * 8) * DFF_ + bc;
    const float* p31 = B3 + (size_t)(k0 + (bs0 + 2) * 8) * DFF_ + bc;
    short8 b10, b11, b30, b31;
    #pragma unroll
    for (int j = 0; j < 8; ++j) {
      b10[j] = (short)f2bf(p10[(size_t)j * DFF_]);
      b11[j] = (short)f2bf(p11[(size_t)j * DFF_]);
      b30[j] = (short)f2bf(p30[(size_t)j * DFF_]);
      b31[j] = (short)f2bf(p31[(size_t)j * DFF_]);
    }
    *(short8*)((char*)Als + aoff0) = av0;
    *(short8*)((char*)Als + aoff1) = av1;
    *(short8*)((char*)B1s + boff0) = b10;
    *(short8*)((char*)B1s + boff1) = b11;
    *(short8*)((char*)B3s + boff0) = b30;
    *(short8*)((char*)B3s + boff1) = b31;
    __syncthreads();

    short8 af[4];
    #pragma unroll
    for (int mi = 0; mi < 4; ++mi)
      af[mi] = *(const short8*)((char*)Als + (((wr << 2) + mi) << 10) + lane * 16);
    #pragma unroll
    for (int ni = 0; ni < 4; ++ni) {
      short8 bf1 = *(const short8*)((char*)B1s + (((wc << 2) + ni) << 10) + lane * 16);
      short8 bf3 = *(const short8*)((char*)B3s + (((wc << 2) + ni) << 10) + lane * 16);
      #pragma unroll
      for (int mi = 0; mi < 4; ++mi) {
        acc1[mi][ni] = __builtin_amdgcn_mfma_f32_16x16x32_bf16(af[mi], bf1, acc1[mi][ni], 0, 0, 0);
        acc3[mi][ni] = __builtin_amdgcn_mfma_f32_16x16x32_bf16(af[mi], bf3, acc3[mi][ni], 0, 0, 0);
      }
    }
  }

  // epilogue: silu(acc1)*acc3 -> bf16 h ; C layout: col=lane&15, row=(lane>>4)*4+j
  int lr = (lane >> 4) << 2;
  int lc = lane & 15;
  #pragma unroll
  for (int mi = 0; mi < 4; ++mi) {
    #pragma unroll
    for (int j = 0; j < 4; ++j) {
      int m = m0 + (wr << 6) + (mi << 4) + lr + j;
      if (m < Me) {
        unsigned short* hp = hptr + (size_t)m * DFF_ + n0 + (wc << 6) + lc;
        #pragma unroll
        for (int ni = 0; ni < 4; ++ni) {
          float a = acc1[mi][ni][j];
          float g = a / (1.f + __expf(-a));
          hp[ni << 4] = f2bf(g * acc3[mi][ni][j]);
        }
      }
    }
  }
}

// ---------------- ffn2: y += w * (h@W2), bf16 MFMA + atomics ----------------
__global__ __launch_bounds__(256) void ffn2_kernel(
    const unsigned short* __restrict__ h, const float* __restrict__ W2,
    const int* __restrict__ counts, const int* __restrict__ rowtok,
    const float* __restrict__ roww, float* __restrict__ y) {
  int e = blockIdx.z;
  int Me = min(counts[e], PAD_);
  int m0 = blockIdx.y * BM;
  if (m0 >= Me) return;
  int n0 = blockIdx.x * BN;

  const unsigned short* A = h + (size_t)(e * PAD_ + m0) * DFF_;
  const float* Bw = W2 + (size_t)e * DFF_ * D_ + n0;

  __shared__ short Als[BM * BK];
  __shared__ short Bs[BK * BN];

  int tid = threadIdx.x;
  int lane = tid & 63;
  int wv = tid >> 6, wr = wv >> 1, wc = wv & 1;

  int arow = tid >> 2, akseg = tid & 3;
  int aoff0 = ((arow >> 4) << 10) + ((akseg << 4) + (arow & 15)) * 16;
  int aoff1 = aoff0 + (4 << 10);
  int bc = tid & 127, bs0 = tid >> 7;
  int boff0 = ((bc >> 4) << 10) + ((bs0 << 4) + (bc & 15)) * 16;
  int boff1 = boff0 + 512;

  f32x4 acc[4][4] = {};

  for (int k0 = 0; k0 < DFF_; k0 += BK) {
    __syncthreads();
    short8 av0 = *(const short8*)(A + (size_t)arow * DFF_ + k0 + akseg * 8);
    short8 av1 = *(const short8*)(A + (size_t)(arow + 64) * DFF_ + k0 + akseg * 8);
    const float* p0 = Bw + (size_t)(k0 + bs0 * 8) * D_ + bc;
    const float* p1 = Bw + (size_t)(k0 + (bs0 + 2) * 8) * D_ + bc;
    short8 b0, b1;
    #pragma unroll
    for (int j = 0; j < 8; ++j) {
      b0[j] = (short)f2bf(p0[(size_t)j * D_]);
      b1[j] = (short)f2bf(p1[(size_t)j * D_]);
    }
    *(short8*)((char*)Als + aoff0) = av0;
    *(short8*)((char*)Als + aoff1) = av1;
    *(short8*)((char*)Bs + boff0) = b0;
    *(short8*)((char*)Bs + boff1) = b1;
    __syncthreads();

    short8 af[4];
    #pragma unroll
    for (int mi = 0; mi < 4; ++mi)
      af[mi] = *(const short8*)((char*)Als + (((wr << 2) + mi) << 10) + lane * 16);
    #pragma unroll
    for (int ni = 0; ni < 4; ++ni) {
      short8 bfr = *(const short8*)((char*)Bs + (((wc << 2) + ni) << 10) + lane * 16);
      #pragma unroll
      for (int mi = 0; mi < 4; ++mi)
        acc[mi][ni] = __builtin_amdgcn_mfma_f32_16x16x32_bf16(af[mi], bfr, acc[mi][ni], 0, 0, 0);
    }
  }

  int lr = (lane >> 4) << 2;
  int lc = lane & 15;
  #pragma unroll
  for (int mi = 0; mi < 4; ++mi) {
    #pragma unroll
    for (int j = 0; j < 4; ++j) {
      int m = m0 + (wr << 6) + (mi << 4) + lr + j;
      if (m < Me) {
        int r = e * PAD_ + m;
        int t = rowtok[r];
        float w = roww[r];
        int b = t >> 11, s = t & (S_ - 1);
        float* yp = y + (size_t)(s * B_ + b) * D_ + n0 + (wc << 6) + lc;
        #pragma unroll
        for (int ni = 0; ni < 4; ++ni)
          atomicAdd(&yp[ni << 4], w * acc[mi][ni][j]);   // exactly 2 adds/elem
      }
    }
  }
}

extern "C" void kernel_launch(void* const* d_in, const int* in_sizes, int n_in,
                              void* d_out, int out_size, void* d_ws, size_t ws_size,
                              hipStream_t stream) {
  const float* x  = (const float*)d_in[0];
  const float* Wg = (const float*)d_in[1];
  const float* W1 = (const float*)d_in[2];
  const float* W3 = (const float*)d_in[3];
  const float* W2 = (const float*)d_in[4];
  float* y = (float*)d_out;
  float* laux = y + (size_t)S_ * B_ * D_;

  char* ws = (char*)d_ws;
  float* probs  = (float*)(ws + OFF_PROBS);
  int*   pe     = (int*)  (ws + OFF_PE);
  float* pw     = (float*)(ws + OFF_PW);
  int*   counts = (int*)  (ws + OFF_COUNTS);
  int*   cursor = (int*)  (ws + OFF_CURSOR);
  float* mesum  = (float*)(ws + OFF_MESUM);
  int*   rowtok = (int*)  (ws + OFF_ROWTOK);
  float* roww   = (float*)(ws + OFF_ROWW);
  unsigned short* xbuf = (unsigned short*)(ws + OFF_XBUF);
  unsigned short* h    = (unsigned short*)(ws + OFF_H);

  hipMemsetAsync(d_out, 0, (size_t)out_size * sizeof(float), stream);
  hipMemsetAsync(counts, 0, 512, stream);  // counts + cursor

  gate_kernel<<<T_, 64, 0, stream>>>(x, Wg, probs, pe, pw, counts);
  me_kernel<<<E_, 256, 0, stream>>>(probs, mesum);
  finalize_kernel<<<1, 64, 0, stream>>>(counts, mesum, laux);
  scatter_kernel<<<NPAIR_, 64, 0, stream>>>(x, pe, pw, cursor, rowtok, roww, xbuf);
  ffn1_kernel<<<dim3(DFF_ / BN, PAD_ / BM, E_), 256, 0, stream>>>(xbuf, W1, W3, counts, h);
  ffn2_kernel<<<dim3(D_ / BN, PAD_ / BM, E_), 256, 0, stream>>>(h, W2, counts, rowtok, roww, y);
}

// Round 3
// 763.490 us; speedup vs baseline: 3.7652x; 1.1929x over previous
//
#include <hip/hip_runtime.h>
#include <hip/hip_bf16.h>

// MoE E=64, top-2, T=8192, D=1024, DFF=1408. Round 3: 2-phase pipelined
// bf16-MFMA FFN (reg-staged prefetch: loads for K-tile t+1 in flight across
// the MFMA phase of tile t). Conflict-free LDS staging (lane->granule linear).
// gate(f32) -> me -> finalize -> scatter(bf16 padded rows) -> ffn1 -> ffn2.

#define S_ 2048
#define B_ 4
#define D_ 1024
#define DFF_ 1408
#define E_ 64
#define T_ 8192
#define KTOP_ 2
#define NPAIR_ (T_*KTOP_)
#define PAD_ 384              // rows/expert (mean 256, sigma 16 -> +8 sigma)
#define ROWS_ (E_*PAD_)

#define BM 128
#define BN 128
#define BK 32

typedef __attribute__((ext_vector_type(8))) short short8;
typedef __attribute__((ext_vector_type(4))) float f32x4;
typedef __attribute__((ext_vector_type(4))) unsigned short us4;

// ---------------- workspace layout (bytes) ----------------
constexpr size_t OFF_PROBS  = 0;
constexpr size_t OFF_PE     = OFF_PROBS + (size_t)T_*E_*4;
constexpr size_t OFF_PW     = OFF_PE + (size_t)NPAIR_*4;
constexpr size_t OFF_COUNTS = OFF_PW + (size_t)NPAIR_*4;
constexpr size_t OFF_CURSOR = OFF_COUNTS + 256;
constexpr size_t OFF_MESUM  = OFF_CURSOR + 256;
constexpr size_t OFF_ROWTOK = OFF_MESUM + 256;
constexpr size_t OFF_ROWW   = OFF_ROWTOK + (size_t)ROWS_*4;
constexpr size_t OFF_XBUF   = OFF_ROWW + (size_t)ROWS_*4;          // bf16 rows
constexpr size_t OFF_H      = OFF_XBUF + (size_t)ROWS_*D_*2;       // bf16 h

__device__ __forceinline__ short f2bfs(float f) {
  union { __hip_bfloat16 h; short s; } u;
  u.h = __float2bfloat16(f);
  return u.s;
}

// ---------------- gate ----------------
__global__ __launch_bounds__(64) void gate_kernel(
    const float* __restrict__ x, const float* __restrict__ Wg,
    float* __restrict__ probs, int* __restrict__ pe, float* __restrict__ pw,
    int* __restrict__ counts) {
  int t = blockIdx.x;
  int lane = threadIdx.x;
  int b = t >> 11, s = t & (S_ - 1);
  const float* tok = x + (size_t)(s * B_ + b) * D_;
  __shared__ float tk[D_];
  for (int i = lane; i < D_; i += 64) tk[i] = tok[i];
  __syncthreads();
  float acc = 0.f;
  #pragma unroll 8
  for (int d = 0; d < D_; ++d) acc += tk[d] * Wg[d * E_ + lane];
  float m = acc;
  for (int o = 32; o; o >>= 1) m = fmaxf(m, __shfl_xor(m, o));
  float p = expf(acc - m);
  float ssum = p;
  for (int o = 32; o; o >>= 1) ssum += __shfl_xor(ssum, o);
  p /= ssum;
  probs[(size_t)t * E_ + lane] = p;
  float v1 = p; int i1 = lane;
  for (int o = 32; o; o >>= 1) {
    float ov = __shfl_xor(v1, o); int oi = __shfl_xor(i1, o);
    if (ov > v1 || (ov == v1 && oi < i1)) { v1 = ov; i1 = oi; }
  }
  float v2 = (lane == i1) ? -1.f : p; int i2 = lane;
  for (int o = 32; o; o >>= 1) {
    float ov = __shfl_xor(v2, o); int oi = __shfl_xor(i2, o);
    if (ov > v2 || (ov == v2 && oi < i2)) { v2 = ov; i2 = oi; }
  }
  if (lane == 0) {
    float wsum = v1 + v2;
    pe[2 * t]     = i1; pw[2 * t]     = v1 / wsum;
    pe[2 * t + 1] = i2; pw[2 * t + 1] = v2 / wsum;
    atomicAdd(&counts[i1], 1);
    atomicAdd(&counts[i2], 1);
  }
}

// ---------------- me reduce ----------------
__global__ __launch_bounds__(256) void me_kernel(const float* __restrict__ probs,
                                                 float* __restrict__ mesum) {
  int e = blockIdx.x, tid = threadIdx.x;
  float a = 0.f;
  for (int t = tid; t < T_; t += 256) a += probs[(size_t)t * E_ + e];
  __shared__ float red[256];
  red[tid] = a; __syncthreads();
  for (int s = 128; s; s >>= 1) {
    if (tid < s) red[tid] += red[tid + s];
    __syncthreads();
  }
  if (tid == 0) mesum[e] = red[0];
}

// ---------------- finalize l_aux ----------------
__global__ __launch_bounds__(64) void finalize_kernel(
    const int* __restrict__ counts, const float* __restrict__ mesum,
    float* __restrict__ laux_out) {
  int lane = threadIdx.x;
  float contrib = (mesum[lane] / (float)T_) * ((float)counts[lane] / (float)(T_ * KTOP_));
  for (int o = 32; o; o >>= 1) contrib += __shfl_xor(contrib, o);
  if (lane == 0) laux_out[0] = (float)E_ * contrib;
}

// ---------------- scatter ----------------
__global__ __launch_bounds__(64) void scatter_kernel(
    const float* __restrict__ x, const int* __restrict__ pe, const float* __restrict__ pw,
    int* __restrict__ cursor, int* __restrict__ rowtok, float* __restrict__ roww,
    unsigned short* __restrict__ xbuf) {
  int p = blockIdx.x;
  int lane = threadIdx.x;
  __shared__ int srow;
  if (lane == 0) {
    int e = pe[p];
    int slot = atomicAdd(&cursor[e], 1);
    int row = (slot < PAD_) ? (e * PAD_ + slot) : -1;
    if (row >= 0) { rowtok[row] = p >> 1; roww[row] = pw[p]; }
    srow = row;
  }
  __syncthreads();
  int row = srow;
  if (row < 0) return;
  int t = p >> 1;
  int b = t >> 11, s = t & (S_ - 1);
  const float4* src = (const float4*)(x + (size_t)(s * B_ + b) * D_);
  unsigned short* dst = xbuf + (size_t)row * D_;
  for (int i = lane; i < D_ / 4; i += 64) {
    float4 v = src[i];
    us4 o;
    o.x = (unsigned short)f2bfs(v.x); o.y = (unsigned short)f2bfs(v.y);
    o.z = (unsigned short)f2bfs(v.z); o.w = (unsigned short)f2bfs(v.w);
    *(us4*)(dst + i * 4) = o;
  }
}

// ---------------- ffn1: h = silu(x@W1) * (x@W3) ----------------
__global__ __launch_bounds__(256, 2) void ffn1_kernel(
    const unsigned short* __restrict__ xbuf, const float* __restrict__ W1,
    const float* __restrict__ W3, const int* __restrict__ counts,
    unsigned short* __restrict__ h) {
  int e = blockIdx.z;
  int Me = min(counts[e], PAD_);
  int m0 = blockIdx.y * BM;
  if (m0 >= Me) return;
  int n0 = blockIdx.x * BN;

  const unsigned short* A = xbuf + (size_t)(e * PAD_ + m0) * D_;
  const float* B1 = W1 + (size_t)e * D_ * DFF_ + n0;
  const float* B3 = W3 + (size_t)e * D_ * DFF_ + n0;
  unsigned short* hptr = h + (size_t)e * PAD_ * DFF_;

  __shared__ short Als[BM * BK];   // 8KB, 16x32 fragment subtiles
  __shared__ short B1s[BK * BN];   // 8KB
  __shared__ short B3s[BK * BN];   // 8KB

  int tid = threadIdx.x;
  int lane = tid & 63;
  int wv = tid >> 6, wr = wv >> 1, wc = wv & 1;

  // A staging: thread (arow=tid>>2, akseg=tid&3) -> rows arow, arow+64
  int arow = tid >> 2, akseg = tid & 3;
  int aoff0 = ((arow >> 4) << 10) + (((akseg << 4) + (arow & 15)) << 4);
  int aoff1 = aoff0 + (4 << 10);
  // B staging: wave wv fills subtiles {2wv, 2wv+1}; lane l -> granule l*16 (linear)
  int bcol0 = (wv << 5) + (lane & 15);
  int bks = lane >> 4;
  int bwoff0 = ((bcol0 >> 4) << 10) + (lane << 4);
  int bwoff1 = bwoff0 + 1024;

  const unsigned short* qa0 = A + (size_t)arow * D_ + akseg * 8;
  const unsigned short* qa1 = A + (size_t)(arow + 64) * D_ + akseg * 8;
  const float* q10 = B1 + (size_t)(bks * 8) * DFF_ + bcol0;
  const float* q11 = q10 + 16;
  const float* q30 = B3 + (size_t)(bks * 8) * DFF_ + bcol0;
  const float* q31 = q30 + 16;

  short8 av0, av1;
  float f10[8], f11[8], f30[8], f31[8];
  f32x4 acc1[4][4] = {};
  f32x4 acc3[4][4] = {};

#define F1_LOAD() do {                                                   \
    av0 = *(const short8*)qa0; av1 = *(const short8*)qa1;                \
    qa0 += BK; qa1 += BK;                                                \
    _Pragma("unroll")                                                    \
    for (int j = 0; j < 8; ++j) {                                        \
      f10[j] = q10[(size_t)j * DFF_]; f11[j] = q11[(size_t)j * DFF_];    \
      f30[j] = q30[(size_t)j * DFF_]; f31[j] = q31[(size_t)j * DFF_];    \
    }                                                                    \
    q10 += (size_t)BK * DFF_; q11 += (size_t)BK * DFF_;                  \
    q30 += (size_t)BK * DFF_; q31 += (size_t)BK * DFF_;                  \
  } while (0)

#define F1_WRITE() do {                                                  \
    short8 s10, s11, s30, s31;                                           \
    _Pragma("unroll")                                                    \
    for (int j = 0; j < 8; ++j) {                                        \
      s10[j] = f2bfs(f10[j]); s11[j] = f2bfs(f11[j]);                    \
      s30[j] = f2bfs(f30[j]); s31[j] = f2bfs(f31[j]);                    \
    }                                                                    \
    *(short8*)((char*)Als + aoff0) = av0;                                \
    *(short8*)((char*)Als + aoff1) = av1;                                \
    *(short8*)((char*)B1s + bwoff0) = s10;                               \
    *(short8*)((char*)B1s + bwoff1) = s11;                               \
    *(short8*)((char*)B3s + bwoff0) = s30;                               \
    *(short8*)((char*)B3s + bwoff1) = s31;                               \
  } while (0)

#define F1_MFMA() do {                                                   \
    short8 af[4];                                                        \
    _Pragma("unroll")                                                    \
    for (int mi = 0; mi < 4; ++mi)                                       \
      af[mi] = *(const short8*)((char*)Als + (((wr << 2) + mi) << 10) + (lane << 4)); \
    _Pragma("unroll")                                                    \
    for (int ni = 0; ni < 4; ++ni) {                                     \
      short8 bf1 = *(const short8*)((char*)B1s + (((wc << 2) + ni) << 10) + (lane << 4)); \
      short8 bf3 = *(const short8*)((char*)B3s + (((wc << 2) + ni) << 10) + (lane << 4)); \
      _Pragma("unroll")                                                  \
      for (int mi = 0; mi < 4; ++mi) {                                   \
        acc1[mi][ni] = __builtin_amdgcn_mfma_f32_16x16x32_bf16(af[mi], bf1, acc1[mi][ni], 0, 0, 0); \
        acc3[mi][ni] = __builtin_amdgcn_mfma_f32_16x16x32_bf16(af[mi], bf3, acc3[mi][ni], 0, 0, 0); \
      }                                                                  \
    }                                                                    \
  } while (0)

  F1_LOAD();
  for (int k0 = BK; k0 < D_; k0 += BK) {
    __syncthreads();
    F1_WRITE();
    __syncthreads();
    F1_LOAD();        // next tile's loads stay in flight across the MFMA phase
    F1_MFMA();
  }
  __syncthreads();
  F1_WRITE();
  __syncthreads();
  F1_MFMA();

  // epilogue: silu(acc1)*acc3 -> bf16 h ; C: col=lane&15, row=(lane>>4)*4+j
  int lr = (lane >> 4) << 2;
  int lc = lane & 15;
  #pragma unroll
  for (int mi = 0; mi < 4; ++mi) {
    #pragma unroll
    for (int j = 0; j < 4; ++j) {
      int m = m0 + (wr << 6) + (mi << 4) + lr + j;
      if (m < Me) {
        unsigned short* hp = hptr + (size_t)m * DFF_ + n0 + (wc << 6) + lc;
        #pragma unroll
        for (int ni = 0; ni < 4; ++ni) {
          float a = acc1[mi][ni][j];
          float g = a / (1.f + __expf(-a));
          hp[ni << 4] = (unsigned short)f2bfs(g * acc3[mi][ni][j]);
        }
      }
    }
  }
}

// ---------------- ffn2: y += w * (h@W2) ----------------
__global__ __launch_bounds__(256, 2) void ffn2_kernel(
    const unsigned short* __restrict__ h, const float* __restrict__ W2,
    const int* __restrict__ counts, const int* __restrict__ rowtok,
    const float* __restrict__ roww, float* __restrict__ y) {
  int e = blockIdx.z;
  int Me = min(counts[e], PAD_);
  int m0 = blockIdx.y * BM;
  if (m0 >= Me) return;
  int n0 = blockIdx.x * BN;

  const unsigned short* A = h + (size_t)(e * PAD_ + m0) * DFF_;
  const float* Bw = W2 + (size_t)e * DFF_ * D_ + n0;

  __shared__ short Als[BM * BK];
  __shared__ short Bs[BK * BN];

  int tid = threadIdx.x;
  int lane = tid & 63;
  int wv = tid >> 6, wr = wv >> 1, wc = wv & 1;

  int arow = tid >> 2, akseg = tid & 3;
  int aoff0 = ((arow >> 4) << 10) + (((akseg << 4) + (arow & 15)) << 4);
  int aoff1 = aoff0 + (4 << 10);
  int bcol0 = (wv << 5) + (lane & 15);
  int bks = lane >> 4;
  int bwoff0 = ((bcol0 >> 4) << 10) + (lane << 4);
  int bwoff1 = bwoff0 + 1024;

  const unsigned short* qa0 = A + (size_t)arow * DFF_ + akseg * 8;
  const unsigned short* qa1 = A + (size_t)(arow + 64) * DFF_ + akseg * 8;
  const float* q20 = Bw + (size_t)(bks * 8) * D_ + bcol0;
  const float* q21 = q20 + 16;

  short8 av0, av1;
  float f20[8], f21[8];
  f32x4 acc[4][4] = {};

#define F2_LOAD() do {                                                   \
    av0 = *(const short8*)qa0; av1 = *(const short8*)qa1;                \
    qa0 += BK; qa1 += BK;                                                \
    _Pragma("unroll")                                                    \
    for (int j = 0; j < 8; ++j) {                                        \
      f20[j] = q20[(size_t)j * D_]; f21[j] = q21[(size_t)j * D_];        \
    }                                                                    \
    q20 += (size_t)BK * D_; q21 += (size_t)BK * D_;                      \
  } while (0)

#define F2_WRITE() do {                                                  \
    short8 s20, s21;                                                     \
    _Pragma("unroll")                                                    \
    for (int j = 0; j < 8; ++j) { s20[j] = f2bfs(f20[j]); s21[j] = f2bfs(f21[j]); } \
    *(short8*)((char*)Als + aoff0) = av0;                                \
    *(short8*)((char*)Als + aoff1) = av1;                                \
    *(short8*)((char*)Bs + bwoff0) = s20;                                \
    *(short8*)((char*)Bs + bwoff1) = s21;                                \
  } while (0)

#define F2_MFMA() do {                                                   \
    short8 af[4];                                                        \
    _Pragma("unroll")                                                    \
    for (int mi = 0; mi < 4; ++mi)                                       \
      af[mi] = *(const short8*)((char*)Als + (((wr << 2) + mi) << 10) + (lane << 4)); \
    _Pragma("unroll")                                                    \
    for (int ni = 0; ni < 4; ++ni) {                                     \
      short8 bfr = *(const short8*)((char*)Bs + (((wc << 2) + ni) << 10) + (lane << 4)); \
      _Pragma("unroll")                                                  \
      for (int mi = 0; mi < 4; ++mi)                                     \
        acc[mi][ni] = __builtin_amdgcn_mfma_f32_16x16x32_bf16(af[mi], bfr, acc[mi][ni], 0, 0, 0); \
    }                                                                    \
  } while (0)

  F2_LOAD();
  for (int k0 = BK; k0 < DFF_; k0 += BK) {
    __syncthreads();
    F2_WRITE();
    __syncthreads();
    F2_LOAD();
    F2_MFMA();
  }
  __syncthreads();
  F2_WRITE();
  __syncthreads();
  F2_MFMA();

  int lr = (lane >> 4) << 2;
  int lc = lane & 15;
  #pragma unroll
  for (int mi = 0; mi < 4; ++mi) {
    #pragma unroll
    for (int j = 0; j < 4; ++j) {
      int m = m0 + (wr << 6) + (mi << 4) + lr + j;
      if (m < Me) {
        int r = e * PAD_ + m;
        int t = rowtok[r];
        float w = roww[r];
        int b = t >> 11, s = t & (S_ - 1);
        float* yp = y + (size_t)(s * B_ + b) * D_ + n0 + (wc << 6) + lc;
        #pragma unroll
        for (int ni = 0; ni < 4; ++ni)
          atomicAdd(&yp[ni << 4], w * acc[mi][ni][j]);   // exactly 2 adds/elem
      }
    }
  }
}

extern "C" void kernel_launch(void* const* d_in, const int* in_sizes, int n_in,
                              void* d_out, int out_size, void* d_ws, size_t ws_size,
                              hipStream_t stream) {
  const float* x  = (const float*)d_in[0];
  const float* Wg = (const float*)d_in[1];
  const float* W1 = (const float*)d_in[2];
  const float* W3 = (const float*)d_in[3];
  const float* W2 = (const float*)d_in[4];
  float* y = (float*)d_out;
  float* laux = y + (size_t)S_ * B_ * D_;

  char* ws = (char*)d_ws;
  float* probs  = (float*)(ws + OFF_PROBS);
  int*   pe     = (int*)  (ws + OFF_PE);
  float* pw     = (float*)(ws + OFF_PW);
  int*   counts = (int*)  (ws + OFF_COUNTS);
  int*   cursor = (int*)  (ws + OFF_CURSOR);
  float* mesum  = (float*)(ws + OFF_MESUM);
  int*   rowtok = (int*)  (ws + OFF_ROWTOK);
  float* roww   = (float*)(ws + OFF_ROWW);
  unsigned short* xbuf = (unsigned short*)(ws + OFF_XBUF);
  unsigned short* h    = (unsigned short*)(ws + OFF_H);

  hipMemsetAsync(d_out, 0, (size_t)out_size * sizeof(float), stream);
  hipMemsetAsync(counts, 0, 512, stream);  // counts + cursor

  gate_kernel<<<T_, 64, 0, stream>>>(x, Wg, probs, pe, pw, counts);
  me_kernel<<<E_, 256, 0, stream>>>(probs, mesum);
  finalize_kernel<<<1, 64, 0, stream>>>(counts, mesum, laux);
  scatter_kernel<<<NPAIR_, 64, 0, stream>>>(x, pe, pw, cursor, rowtok, roww, xbuf);
  ffn1_kernel<<<dim3(DFF_ / BN, PAD_ / BM, E_), 256, 0, stream>>>(xbuf, W1, W3, counts, h);
  ffn2_kernel<<<dim3(D_ / BN, PAD_ / BM, E_), 256, 0, stream>>>(h, W2, counts, rowtok, roww, y);
}